// Round 8
// baseline (434.041 us; speedup 1.0000x reference)
//
#include <hip/hip_runtime.h>
#include <math.h>

#define BB 16
#define NN 1024
#define MM 1024
#define DKK 512
#define RBLK 16                  // rows per sink_iter block
#define NRB  (NN/RBLK)           // 64 row-blocks per batch
#define LSTR 1032                // sink_iter LDS row stride (8r+c bank pattern: 2-way, free)

typedef short short8 __attribute__((ext_vector_type(8)));
typedef float f32x4 __attribute__((ext_vector_type(4)));

// scratch as device globals (fully rewritten every call)
__device__ float g_u[BB*NN];
__device__ float g_v[BB*MM];
__device__ float g_w[BB*NN];
__device__ float g_wt[BB*3*NN];
__device__ float g_pm[BB*NRB*MM];   // col-lse partial max
__device__ float g_ps[BB*NRB*MM];   // col-lse partial sum
// split-bf16 operands, [B][N][DK] k-contiguous, chunk-swizzled (see convert_split)
__device__ __attribute__((aligned(16))) unsigned short gAh[BB*NN*DKK];
__device__ __attribute__((aligned(16))) unsigned short gAl[BB*NN*DKK];
__device__ __attribute__((aligned(16))) unsigned short gBh[BB*MM*DKK];
__device__ __attribute__((aligned(16))) unsigned short gBl[BB*MM*DKK];

__device__ __forceinline__ unsigned int bf16_rne(float x){
    unsigned int u = __float_as_uint(x);
    return (u + 0x7fffu + ((u>>16)&1u)) >> 16;
}

// async global->LDS DMA, 16B per lane; LDS dest = wave-uniform base + lane*16
__device__ __forceinline__ void gl_lds(const void* g, void* l){
    __builtin_amdgcn_global_load_lds(
        (const __attribute__((address_space(1))) unsigned int*)g,
        (__attribute__((address_space(3))) unsigned int*)l, 16, 0, 0);
}

// X [16][512][1024] fp32 -> hi/lo bf16 [16][1024][512], transposed, with the
// 16B-chunk swizzle baked in: semantic chunk p (within a row) is stored at
// slot (p&4)|((p + (row>>1))&3) so gemm's lane-contiguous global_load_lds
// staging yields conflict-free LDS fragment reads.
// z: 0..31 -> which = z>>4 (0=A,1=B), b = z&15.
__global__ __launch_bounds__(256) void convert_split(const float* __restrict__ A,
                                                     const float* __restrict__ Bm) {
    int z = blockIdx.z;
    int which = z >> 4;
    int b = z & 15;
    int t = threadIdx.x;
    const float* X = which ? Bm : A;
    unsigned short* Hh = which ? gBh : gAh;
    unsigned short* Hl = which ? gBl : gAl;
    int d0 = blockIdx.y * 64;
    int i0 = blockIdx.x * 64;
    __shared__ float T[64*65];
    const float* Xb = X + ((size_t)b*DKK + d0)*NN + i0;
#pragma unroll
    for (int it=0; it<4; ++it){
        int lin = t + 256*it;
        int d = lin >> 4;
        int i4 = lin & 15;
        float4 v = *(const float4*)(Xb + (size_t)d*NN + i4*4);
        T[(i4*4+0)*65 + d] = v.x;
        T[(i4*4+1)*65 + d] = v.y;
        T[(i4*4+2)*65 + d] = v.z;
        T[(i4*4+3)*65 + d] = v.w;
    }
    __syncthreads();
    size_t obase = ((size_t)b*NN + i0)*DKK + d0;
#pragma unroll
    for (int it=0; it<2; ++it){
        int c = t + 256*it;
        int i = c >> 3;            // row 0..63 within i0 block
        int p = c & 7;             // semantic 16B chunk within this 64-d block
        unsigned int hw[4], lw[4];
#pragma unroll
        for (int j=0;j<4;j++){
            float x0 = T[i*65 + p*8 + 2*j];
            float x1 = T[i*65 + p*8 + 2*j+1];
            unsigned int h0 = bf16_rne(x0);
            unsigned int h1 = bf16_rne(x1);
            float hf0 = __uint_as_float(h0<<16);
            float hf1 = __uint_as_float(h1<<16);
            unsigned int l0 = bf16_rne(x0 - hf0);
            unsigned int l1 = bf16_rne(x1 - hf1);
            hw[j] = h0 | (h1<<16);
            lw[j] = l0 | (l1<<16);
        }
        int pw = (p & 4) | ((p + (i>>1)) & 3);   // swizzled slot
        size_t eo = obase + (size_t)i*DKK + pw*8;
        uint4 hv; hv.x=hw[0]; hv.y=hw[1]; hv.z=hw[2]; hv.w=hw[3];
        uint4 lv; lv.x=lw[0]; lv.y=lw[1]; lv.z=lw[2]; lv.w=lw[3];
        *(uint4*)(Hh + eo) = hv;
        *(uint4*)(Hl + eo) = lv;
    }
}

// C[b][i][j] = (sum_d A[d][i]*B[d][j]) / (sqrt(512)*temp[b]) via split-bf16 MFMA.
// 256x256 tile per block, 8 waves (2Mx4N), BK=32, 16 K-steps.
// 3 phases per K-step (hh, lh, hl) -- best measured schedule (R1, 50.5 us).
// Counted-vmcnt pipeline, never drained to 0 mid-loop; setprio around MFMA.
// NOTE: operand stream (268 MB, ~2x redundancy) is L3-served at ~5.2 TB/s --
// measured invariant across 4 schedule variants => fetch-bound; do not retune.
__global__ __launch_bounds__(512,2) void gemm_mfma(const float* __restrict__ temp,
                                                   float* __restrict__ C) {
    int id   = blockIdx.x;
    int xcd  = id & 7;
    int slot = id >> 3;             // 0..31
    int b    = xcd*2 + (slot >> 4); // batch pinned to XCD (L2 locality)
    int sub  = slot & 15;
    int i0   = (sub >> 2) << 8;
    int j0   = (sub & 3) << 8;
    __shared__ __attribute__((aligned(16))) char lds[131072];
    int t = threadIdx.x;
    int lane = t & 63, w = t >> 6;      // 8 waves
    int wr = w >> 2, wc = w & 3;        // 2 x 4 wave grid, per wave 128x64 out

    int rql = lane >> 2, cl = lane & 3;
    unsigned eoff = (unsigned)(b * (NN*DKK*2));
    unsigned offA = eoff + (unsigned)((i0 + w*32 + rql)*1024) + (unsigned)(cl*16);
    unsigned offB = eoff + (unsigned)((j0 + w*32 + rql)*1024) + (unsigned)(cl*16);
    int dq0 = w*2048;                   // LDS dst base for q=0 (q=1: +1024)

    const char* pAh = (const char*)gAh;
    const char* pAl = (const char*)gAl;
    const char* pBh = (const char*)gBh;
    const char* pBl = (const char*)gBl;
    // LDS unit bases: Ah 0/16384, Al 32768/49152, Bh 65536/81920, Bl 98304/114688

    f32x4 acc[32];
#pragma unroll
    for (int q=0;q<32;q++) acc[q] = (f32x4){0.f,0.f,0.f,0.f};

    int fslot = ((lane>>4) + ((lane&15)>>1)) & 3;
    int faoff = (wr*128 + (lane&15))*64 + fslot*16;   // + mf*1024
    int fboff = (wc*64  + (lane&15))*64 + fslot*16;   // + nf*1024

    // prologue: stage ks=0, issue order AhBh (4), Al (2), Bl (2)
    gl_lds(pAh + offA,          lds + 0      + dq0);
    gl_lds(pAh + offA + 16384,  lds + 0      + dq0 + 1024);
    gl_lds(pBh + offB,          lds + 65536  + dq0);
    gl_lds(pBh + offB + 16384,  lds + 65536  + dq0 + 1024);
    gl_lds(pAl + offA,          lds + 32768  + dq0);
    gl_lds(pAl + offA + 16384,  lds + 32768  + dq0 + 1024);
    gl_lds(pBl + offB,          lds + 98304  + dq0);
    gl_lds(pBl + offB + 16384,  lds + 98304  + dq0 + 1024);

    short8 ah[8], bh[4], al[8], bl[4];

    for (int ks=0; ks<16; ++ks){
        int par = (ks & 1) << 14;       // current buffer parity offset
        int nxt = 16384 - par;

        // ================= phase A : hh =================
        asm volatile("s_waitcnt vmcnt(4)" ::: "memory");
        __builtin_amdgcn_s_barrier();
        __builtin_amdgcn_sched_barrier(0);
        {
            const char* fa = lds + par + faoff;
            const char* fb = lds + 65536 + par + fboff;
#pragma unroll
            for (int mf=0;mf<8;mf++) ah[mf] = *(const short8*)(fa + mf*1024);
#pragma unroll
            for (int nf=0;nf<4;nf++) bh[nf] = *(const short8*)(fb + nf*1024);
        }
        if (ks < 15){
            offA += 64; offB += 64;
            gl_lds(pAh + offA,         lds + 0     + nxt + dq0);
            gl_lds(pAh + offA + 16384, lds + 0     + nxt + dq0 + 1024);
            gl_lds(pBh + offB,         lds + 65536 + nxt + dq0);
            gl_lds(pBh + offB + 16384, lds + 65536 + nxt + dq0 + 1024);
        }
        asm volatile("s_waitcnt lgkmcnt(0)" ::: "memory");
        __builtin_amdgcn_sched_barrier(0);
        __builtin_amdgcn_s_setprio(1);
#pragma unroll
        for (int nf=0;nf<4;nf++)
#pragma unroll
            for (int mf=0;mf<8;mf++)
                acc[mf*4+nf] = __builtin_amdgcn_mfma_f32_16x16x32_bf16(ah[mf], bh[nf], acc[mf*4+nf], 0,0,0);
        __builtin_amdgcn_s_setprio(0);
        __builtin_amdgcn_sched_barrier(0);

        // ================= phase B : lh =================
        if (ks < 15) asm volatile("s_waitcnt vmcnt(6)" ::: "memory");
        else         asm volatile("s_waitcnt vmcnt(2)" ::: "memory");
        __builtin_amdgcn_s_barrier();
        __builtin_amdgcn_sched_barrier(0);
        {
            const char* fa = lds + 32768 + par + faoff;
#pragma unroll
            for (int mf=0;mf<8;mf++) al[mf] = *(const short8*)(fa + mf*1024);
        }
        if (ks < 15){
            gl_lds(pAl + offA,         lds + 32768 + nxt + dq0);
            gl_lds(pAl + offA + 16384, lds + 32768 + nxt + dq0 + 1024);
        }
        asm volatile("s_waitcnt lgkmcnt(0)" ::: "memory");
        __builtin_amdgcn_sched_barrier(0);
        __builtin_amdgcn_s_setprio(1);
#pragma unroll
        for (int nf=0;nf<4;nf++)
#pragma unroll
            for (int mf=0;mf<8;mf++)
                acc[mf*4+nf] = __builtin_amdgcn_mfma_f32_16x16x32_bf16(al[mf], bh[nf], acc[mf*4+nf], 0,0,0);
        __builtin_amdgcn_s_setprio(0);
        __builtin_amdgcn_sched_barrier(0);

        // ================= phase C : hl =================
        if (ks < 15) asm volatile("s_waitcnt vmcnt(6)" ::: "memory");
        else         asm volatile("s_waitcnt vmcnt(0)" ::: "memory");
        __builtin_amdgcn_s_barrier();
        __builtin_amdgcn_sched_barrier(0);
        {
            const char* fb = lds + 98304 + par + fboff;
#pragma unroll
            for (int nf=0;nf<4;nf++) bl[nf] = *(const short8*)(fb + nf*1024);
        }
        if (ks < 15){
            gl_lds(pBl + offB,         lds + 98304 + nxt + dq0);
            gl_lds(pBl + offB + 16384, lds + 98304 + nxt + dq0 + 1024);
        }
        asm volatile("s_waitcnt lgkmcnt(0)" ::: "memory");
        __builtin_amdgcn_sched_barrier(0);
        __builtin_amdgcn_s_setprio(1);
#pragma unroll
        for (int nf=0;nf<4;nf++)
#pragma unroll
            for (int mf=0;mf<8;mf++)
                acc[mf*4+nf] = __builtin_amdgcn_mfma_f32_16x16x32_bf16(ah[mf], bl[nf], acc[mf*4+nf], 0,0,0);
        __builtin_amdgcn_s_setprio(0);
        __builtin_amdgcn_sched_barrier(0);
    }

    float scale = 1.0f/(22.62741699796952f * temp[b]);
    float* Cb = C + ((size_t)b<<20);
    int r0c = i0 + wr*128 + ((lane>>4)<<2);
    int c0c = j0 + wc*64 + (lane&15);
#pragma unroll
    for (int mf=0;mf<8;mf++){
#pragma unroll
        for (int r2=0;r2<4;r2++){
            float* rowp = Cb + (size_t)(r0c + mf*16 + r2)*MM + c0c;
#pragma unroll
            for (int nf=0;nf<4;nf++)
                rowp[nf*16] = acc[mf*4+nf][r2]*scale;
        }
    }
}

// One fused Sinkhorn iteration. Prologue (first==0): compute this batch's v
// in-block from g_pm/g_ps (col-LSE over 64 partials, 4 cols/thread, 1 exp per
// merge step) -- redundant per block but L2-hot, replaces the separate
// col_lse_combine dispatch between iterations. first==1: v == 0 (reference's
// first op is the row normalization of raw scores).
__global__ __launch_bounds__(256) void sink_iter(const float* __restrict__ S,
                                                 int first) {
    int b   = blockIdx.y;
    int rb  = blockIdx.x;
    int row0 = rb*RBLK;
    int t = threadIdx.x;
    __shared__ float Ls[RBLK*LSTR];
    __shared__ float v_l[1024];
    __shared__ float u_l[RBLK];

    if (first){
        *(float4*)(v_l + t*4) = make_float4(0.f,0.f,0.f,0.f);
    } else {
        float m[4], s[4];
#pragma unroll
        for (int k=0;k<4;k++){ m[k] = -INFINITY; s[k] = 0.0f; }
        size_t base = ((size_t)(b*NRB) << 10) + t;
        for (int c=0;c<NRB;++c){
            size_t o = base + ((size_t)c<<10);
#pragma unroll
            for (int k=0;k<4;k++){
                float om = g_pm[o + 256*k];
                float os = g_ps[o + 256*k];
                float d  = om - m[k];
                float e  = __expf(-fabsf(d));
                if (d > 0.0f){ s[k] = s[k]*e + os; m[k] = om; }
                else         { s[k] += os*e; }
            }
        }
#pragma unroll
        for (int k=0;k<4;k++){
            float nm = fmaxf(m[k], 0.0f);
            float Sx = s[k]*__expf(m[k]-nm) + __expf(-nm);
            v_l[t + 256*k] = nm + __logf(Sx);
        }
    }
    __syncthreads();
    float4 v4 = *(const float4*)(v_l + t*4);

    const float* Sb = S + ((size_t)b*NN + row0)*MM;
#pragma unroll
    for (int rr=0; rr<RBLK; ++rr){
        float4 s4 = *(const float4*)(Sb + (size_t)rr*MM + t*4);
        s4.x -= v4.x; s4.y -= v4.y; s4.z -= v4.z; s4.w -= v4.w;
        *(float4*)(&Ls[rr*LSTR + t*4]) = s4;
    }
    __syncthreads();

    {
        int r = t >> 4, c = t & 15;
        const float* Lr = &Ls[r*LSTR + c];
        float m = -INFINITY;
#pragma unroll
        for (int k=0;k<64;k++) m = fmaxf(m, Lr[16*k]);
#pragma unroll
        for (int off=1; off<16; off<<=1) m = fmaxf(m, __shfl_xor(m, off));
        m = fmaxf(m, 0.0f);
        float s = 0.0f;
#pragma unroll
        for (int k=0;k<64;k++) s += __expf(Lr[16*k] - m);
#pragma unroll
        for (int off=1; off<16; off<<=1) s += __shfl_xor(s, off);
        s += __expf(-m);
        float u = m + __logf(s);
        if (c==0){ u_l[r] = u; g_u[b*NN + row0 + r] = u; }
    }
    __syncthreads();

    float mm[4], ss[4];
#pragma unroll
    for (int q=0;q<4;q++){ mm[q]=-INFINITY; ss[q]=0.f; }
#pragma unroll
    for (int r=0;r<RBLK;++r){
        float ur = u_l[r];
        const float* Lr = &Ls[r*LSTR];
#pragma unroll
        for (int q=0;q<4;q++)
            mm[q] = fmaxf(mm[q], Lr[t + 256*q] - ur);
    }
#pragma unroll
    for (int r=0;r<RBLK;++r){
        float ur = u_l[r];
        const float* Lr = &Ls[r*LSTR];
#pragma unroll
        for (int q=0;q<4;q++)
            ss[q] += __expf(Lr[t + 256*q] - ur - mm[q]);
    }
    size_t pbase = ((size_t)(b*NRB + rb) << 10) + t;
#pragma unroll
    for (int q=0;q<4;q++){
        g_pm[pbase + 256*q] = mm[q] + v_l[t + 256*q];
        g_ps[pbase + 256*q] = ss[q];
    }
}

// Final column LSE combine (iteration 5 only): produces g_v for finalize_rows.
// 8 independent LSE chains over the 64 partials + associative merge.
__global__ __launch_bounds__(64) void col_lse_combine() {
    int idx = blockIdx.x*64 + threadIdx.x;
    int b = idx >> 10; int j = idx & (MM-1);
    size_t base = ((size_t)(b*NRB) << 10) + j;
    float m[8], s[8];
#pragma unroll
    for (int k=0;k<8;k++){ m[k] = -INFINITY; s[k] = 0.0f; }
    for (int c=0;c<NRB;c+=8){
#pragma unroll
        for (int k=0;k<8;k++){
            float om = g_pm[base + ((size_t)(c+k)<<10)];
            float os = g_ps[base + ((size_t)(c+k)<<10)];
            float nm = fmaxf(m[k], om);
            s[k] = s[k]*__expf(m[k]-nm) + os*__expf(om-nm);
            m[k] = nm;
        }
    }
#pragma unroll
    for (int st=1; st<8; st<<=1){
#pragma unroll
        for (int k=0;k<8;k+=2*st){
            float nm = fmaxf(m[k], m[k+st]);
            s[k] = s[k]*__expf(m[k]-nm) + s[k+st]*__expf(m[k+st]-nm);
            m[k] = nm;
        }
    }
    float nm = fmaxf(m[0], 0.0f);
    float Sx = s[0]*__expf(m[0]-nm) + __expf(-nm);
    g_v[idx] = nm + __logf(Sx);
}

__global__ __launch_bounds__(256) void finalize_rows(float* __restrict__ S,
                                                     const float* __restrict__ tgt) {
    int row  = blockIdx.x*4 + (threadIdx.x>>6);
    int lane = threadIdx.x & 63;
    int b = row >> 10;
    int i = row & (NN-1);
    float ui = g_u[row];
    float4* srow = (float4*)(S + (size_t)row*MM);
    const float4* vb = (const float4*)(g_v + (b<<10));
    const float4* t0 = (const float4*)(tgt + (size_t)b*3*MM);
    const float4* t1 = (const float4*)(tgt + (size_t)b*3*MM + MM);
    const float4* t2 = (const float4*)(tgt + (size_t)b*3*MM + 2*MM);
    float p[16];
    float rs=0.f, a0=0.f, a1=0.f, a2=0.f;
#pragma unroll
    for (int k=0;k<4;k++){
        float4 s4 = srow[lane + 64*k];
        float4 v4 = vb[lane + 64*k];
        p[4*k+0] = __expf(s4.x - ui - v4.x);
        p[4*k+1] = __expf(s4.y - ui - v4.y);
        p[4*k+2] = __expf(s4.z - ui - v4.z);
        p[4*k+3] = __expf(s4.w - ui - v4.w);
        rs += p[4*k+0]+p[4*k+1]+p[4*k+2]+p[4*k+3];
        float4 w0 = t0[lane + 64*k];
        float4 w1 = t1[lane + 64*k];
        float4 w2 = t2[lane + 64*k];
        a0 += p[4*k+0]*w0.x + p[4*k+1]*w0.y + p[4*k+2]*w0.z + p[4*k+3]*w0.w;
        a1 += p[4*k+0]*w1.x + p[4*k+1]*w1.y + p[4*k+2]*w1.z + p[4*k+3]*w1.w;
        a2 += p[4*k+0]*w2.x + p[4*k+1]*w2.y + p[4*k+2]*w2.z + p[4*k+3]*w2.w;
    }
    for (int off=32; off; off>>=1){
        rs += __shfl_xor(rs, off);
        a0 += __shfl_xor(a0, off);
        a1 += __shfl_xor(a1, off);
        a2 += __shfl_xor(a2, off);
    }
    float inv = 1.0f/(rs + 1e-8f);
#pragma unroll
    for (int k=0;k<4;k++){
        srow[lane + 64*k] = make_float4(p[4*k+0]*inv, p[4*k+1]*inv, p[4*k+2]*inv, p[4*k+3]*inv);
    }
    if (lane==0){
        g_w[row] = rs;
        g_wt[(b*3+0)*NN + i] = a0*inv;
        g_wt[(b*3+1)*NN + i] = a1*inv;
        g_wt[(b*3+2)*NN + i] = a2*inv;
    }
}

// Register-resident 3-pass Procrustes: each thread loads its 28 values once,
// reductions via wave shuffle + 4-partial LDS combine (3 barriers total).
__global__ __launch_bounds__(256) void procrustes(const float* __restrict__ src,
                                                  float* __restrict__ out) {
    int b = blockIdx.x;
    int t = threadIdx.x;
    int lane = t & 63, w = t >> 6;
    __shared__ float part[4][16];
    const float* wrow = g_w + b*NN;
    const float* sb  = src  + (size_t)b*3*NN;
    const float* wtb = g_wt + (size_t)b*3*NN;

    float wv[4], sv[3][4], tv3[3][4];
#pragma unroll
    for (int k=0;k<4;k++){
        int i = t + 256*k;
        wv[k] = wrow[i];
#pragma unroll
        for (int c=0;c<3;c++){
            sv[c][k]  = sb[c*NN+i];
            tv3[c][k] = wtb[c*NN+i];
        }
    }

    auto block_reduce = [&](float* v, int nv){
        for (int jx=0;jx<nv;jx++){
            float x = v[jx];
            for (int off=32;off;off>>=1) x += __shfl_xor(x, off);
            if (lane==0) part[w][jx] = x;
        }
        __syncthreads();
        for (int jx=0;jx<nv;jx++)
            v[jx] = part[0][jx]+part[1][jx]+part[2][jx]+part[3][jx];
        __syncthreads();
    };

    float W = wv[0]+wv[1]+wv[2]+wv[3];
    block_reduce(&W, 1);
    float winv = 1.0f/(W + 1e-8f);
    float wn[4];
#pragma unroll
    for (int k=0;k<4;k++) wn[k] = wv[k]*winv;

    float a[6];
#pragma unroll
    for (int c=0;c<3;c++){
        float p1=0.f,p2=0.f;
#pragma unroll
        for (int k=0;k<4;k++){ p1 += sv[c][k]*wn[k]; p2 += tv3[c][k]*wn[k]; }
        a[c]=p1; a[3+c]=p2;
    }
    block_reduce(a, 6);
    float sc[3], tc[3];
#pragma unroll
    for (int c=0;c<3;c++){ sc[c]=a[c]; tc[c]=a[3+c]; }

    float H[9];
#pragma unroll
    for (int c=0;c<3;c++)
#pragma unroll
        for (int d=0;d<3;d++){
            float p=0.f;
#pragma unroll
            for (int k=0;k<4;k++)
                p += (sv[c][k]-sc[c]) * ((tv3[d][k]-tc[d])*wn[k]);
            H[c*3+d]=p;
        }
    block_reduce(H, 9);

    if (t==0){
        double Hd[3][3];
        for (int r2=0;r2<3;r2++) for (int c2=0;c2<3;c2++) Hd[r2][c2]=H[r2*3+c2];
        double K[3][3];
        for (int i2=0;i2<3;i2++)
            for (int j2=0;j2<3;j2++){
                double acc=0;
                for (int r2=0;r2<3;r2++) acc += Hd[r2][i2]*Hd[r2][j2];
                K[i2][j2]=acc;
            }
        double V[3][3]={{1,0,0},{0,1,0},{0,0,1}};
        const int PQ[3][2]={{0,1},{0,2},{1,2}};
        for (int sweep=0; sweep<30; ++sweep){
            double off = fabs(K[0][1])+fabs(K[0][2])+fabs(K[1][2]);
            if (off < 1e-26) break;
            for (int pi=0; pi<3; ++pi){
                int p = PQ[pi][0], q = PQ[pi][1];
                double apq = K[p][q];
                if (fabs(apq) < 1e-300) continue;
                double tau = (K[q][q]-K[p][p])/(2.0*apq);
                double tt  = (tau>=0.0?1.0:-1.0)/(fabs(tau)+sqrt(1.0+tau*tau));
                double c   = 1.0/sqrt(1.0+tt*tt);
                double s   = tt*c;
                double Kpp=K[p][p], Kqq=K[q][q];
                K[p][p] = Kpp - tt*apq;
                K[q][q] = Kqq + tt*apq;
                K[p][q] = 0.0; K[q][p] = 0.0;
                int r2 = 3-p-q;
                double Krp=K[r2][p], Krq=K[r2][q];
                K[r2][p] = c*Krp - s*Krq; K[p][r2]=K[r2][p];
                K[r2][q] = s*Krp + c*Krq; K[q][r2]=K[r2][q];
                for (int rr=0; rr<3; ++rr){
                    double vp=V[rr][p], vq=V[rr][q];
                    V[rr][p] = c*vp - s*vq;
                    V[rr][q] = s*vp + c*vq;
                }
            }
        }
        double lam[3]={K[0][0],K[1][1],K[2][2]};
        int o0=0,o1=1,o2=2,tmp;
        if (lam[o0]<lam[o1]){tmp=o0;o0=o1;o1=tmp;}
        if (lam[o0]<lam[o2]){tmp=o0;o0=o2;o2=tmp;}
        if (lam[o1]<lam[o2]){tmp=o1;o1=o2;o2=tmp;}
        int ord[3]={o0,o1,o2};
        double Vs[3][3], U[3][3];
        for (int k=0;k<3;k++)
            for (int r2=0;r2<3;r2++) Vs[r2][k]=V[r2][ord[k]];
        for (int k=0;k<3;k++){
            double ux = Hd[0][0]*Vs[0][k] + Hd[0][1]*Vs[1][k] + Hd[0][2]*Vs[2][k];
            double uy = Hd[1][0]*Vs[0][k] + Hd[1][1]*Vs[1][k] + Hd[1][2]*Vs[2][k];
            double uz = Hd[2][0]*Vs[0][k] + Hd[2][1]*Vs[1][k] + Hd[2][2]*Vs[2][k];
            double n = sqrt(ux*ux+uy*uy+uz*uz);
            if (n > 1e-30){ U[0][k]=ux/n; U[1][k]=uy/n; U[2][k]=uz/n; }
            else {
                double cx = U[1][0]*U[2][1]-U[2][0]*U[1][1];
                double cy = U[2][0]*U[0][1]-U[0][0]*U[2][1];
                double cz = U[0][0]*U[1][1]-U[1][0]*U[0][1];
                U[0][k]=cx; U[1][k]=cy; U[2][k]=cz;
            }
        }
        double rm[3][3];
        for (int i2=0;i2<3;i2++)
            for (int j2=0;j2<3;j2++)
                rm[i2][j2] = Vs[i2][0]*U[j2][0] + Vs[i2][1]*U[j2][1] + Vs[i2][2]*U[j2][2];
        double det = rm[0][0]*(rm[1][1]*rm[2][2]-rm[1][2]*rm[2][1])
                   - rm[0][1]*(rm[1][0]*rm[2][2]-rm[1][2]*rm[2][0])
                   + rm[0][2]*(rm[1][0]*rm[2][1]-rm[1][1]*rm[2][0]);
        double R[3][3];
        for (int i2=0;i2<3;i2++)
            for (int j2=0;j2<3;j2++)
                R[i2][j2] = Vs[i2][0]*U[j2][0] + Vs[i2][1]*U[j2][1] + det*Vs[i2][2]*U[j2][2];
        double tvv[3];
        for (int i2=0;i2<3;i2++)
            tvv[i2] = -(R[i2][0]*sc[0]+R[i2][1]*sc[1]+R[i2][2]*sc[2]) + tc[i2];
        for (int i2=0;i2<3;i2++)
            for (int j2=0;j2<3;j2++)
                out[b*9 + i2*3 + j2] = (float)R[i2][j2];
        for (int i2=0;i2<3;i2++)
            out[144 + b*3 + i2] = (float)tvv[i2];
    }
}

extern "C" void kernel_launch(void* const* d_in, const int* in_sizes, int n_in,
                              void* d_out, int out_size, void* d_ws, size_t ws_size,
                              hipStream_t stream) {
    const float* src_emb = (const float*)d_in[0];
    const float* tgt_emb = (const float*)d_in[1];
    const float* src     = (const float*)d_in[2];
    const float* tgt     = (const float*)d_in[3];
    const float* temp    = (const float*)d_in[4];
    float* out = (float*)d_out;
    float* S = out + 192;   // perm_norm region doubles as scores buffer

    hipLaunchKernelGGL(convert_split, dim3(16,8,32), dim3(256), 0, stream, src_emb, tgt_emb);
    hipLaunchKernelGGL(gemm_mfma, dim3(256), dim3(512), 0, stream, temp, S);
    hipLaunchKernelGGL(sink_iter, dim3(NRB,BB), dim3(256), 0, stream, S, 1);
    for (int it=1; it<5; ++it)
        hipLaunchKernelGGL(sink_iter, dim3(NRB,BB), dim3(256), 0, stream, S, 0);
    hipLaunchKernelGGL(col_lse_combine, dim3(256), dim3(64), 0, stream);
    hipLaunchKernelGGL(finalize_rows, dim3(4096), dim3(256), 0, stream, S, tgt);
    hipLaunchKernelGGL(procrustes, dim3(16), dim3(256), 0, stream, src, out);
}

// Round 9
// 331.650 us; speedup vs baseline: 1.3087x; 1.3087x over previous
//
#include <hip/hip_runtime.h>
#include <math.h>

#define BB 16
#define NN 1024
#define MM 1024
#define DKK 512
#define RBLK 16                  // rows per sink_iter block
#define NRB  (NN/RBLK)           // 64 row-blocks per batch
#define LSTR 1032                // sink_iter LDS row stride (8r+c bank pattern: 2-way, free)

typedef short short8 __attribute__((ext_vector_type(8)));
typedef float f32x4 __attribute__((ext_vector_type(4)));

// scratch as device globals (fully rewritten every call)
__device__ float g_u[BB*NN];
__device__ float g_v[BB*MM];
__device__ float g_w[BB*NN];
__device__ float g_wt[BB*3*NN];
__device__ float g_pm[BB*NRB*MM];   // col-lse partial max
__device__ float g_ps[BB*NRB*MM];   // col-lse partial sum
// split-bf16 operands, [B][N][DK] k-contiguous, chunk-swizzled (see convert_split)
__device__ __attribute__((aligned(16))) unsigned short gAh[BB*NN*DKK];
__device__ __attribute__((aligned(16))) unsigned short gAl[BB*NN*DKK];
__device__ __attribute__((aligned(16))) unsigned short gBh[BB*MM*DKK];
__device__ __attribute__((aligned(16))) unsigned short gBl[BB*MM*DKK];

__device__ __forceinline__ unsigned int bf16_rne(float x){
    unsigned int u = __float_as_uint(x);
    return (u + 0x7fffu + ((u>>16)&1u)) >> 16;
}

// async global->LDS DMA, 16B per lane; LDS dest = wave-uniform base + lane*16
__device__ __forceinline__ void gl_lds(const void* g, void* l){
    __builtin_amdgcn_global_load_lds(
        (const __attribute__((address_space(1))) unsigned int*)g,
        (__attribute__((address_space(3))) unsigned int*)l, 16, 0, 0);
}

// X [16][512][1024] fp32 -> hi/lo bf16 [16][1024][512], transposed, with the
// 16B-chunk swizzle baked in: semantic chunk p (within a row) is stored at
// slot (p&4)|((p + (row>>1))&3) so gemm's lane-contiguous global_load_lds
// staging yields conflict-free LDS fragment reads.
// z: 0..31 -> which = z>>4 (0=A,1=B), b = z&15.
// Also: the 16 blocks with (z==0, y==0) zero g_v (folds the old zero_v launch).
__global__ __launch_bounds__(256) void convert_split(const float* __restrict__ A,
                                                     const float* __restrict__ Bm) {
    int z = blockIdx.z;
    int which = z >> 4;
    int b = z & 15;
    int t = threadIdx.x;
    if (z == 0 && blockIdx.y == 0){
        // 16 blocks x 256 threads x float4 = 16384 floats
        *(float4*)(g_v + blockIdx.x*1024 + t*4) = make_float4(0.f,0.f,0.f,0.f);
    }
    const float* X = which ? Bm : A;
    unsigned short* Hh = which ? gBh : gAh;
    unsigned short* Hl = which ? gBl : gAl;
    int d0 = blockIdx.y * 64;
    int i0 = blockIdx.x * 64;
    __shared__ float T[64*65];
    const float* Xb = X + ((size_t)b*DKK + d0)*NN + i0;
#pragma unroll
    for (int it=0; it<4; ++it){
        int lin = t + 256*it;
        int d = lin >> 4;
        int i4 = lin & 15;
        float4 v = *(const float4*)(Xb + (size_t)d*NN + i4*4);
        T[(i4*4+0)*65 + d] = v.x;
        T[(i4*4+1)*65 + d] = v.y;
        T[(i4*4+2)*65 + d] = v.z;
        T[(i4*4+3)*65 + d] = v.w;
    }
    __syncthreads();
    size_t obase = ((size_t)b*NN + i0)*DKK + d0;
#pragma unroll
    for (int it=0; it<2; ++it){
        int c = t + 256*it;
        int i = c >> 3;            // row 0..63 within i0 block
        int p = c & 7;             // semantic 16B chunk within this 64-d block
        unsigned int hw[4], lw[4];
#pragma unroll
        for (int j=0;j<4;j++){
            float x0 = T[i*65 + p*8 + 2*j];
            float x1 = T[i*65 + p*8 + 2*j+1];
            unsigned int h0 = bf16_rne(x0);
            unsigned int h1 = bf16_rne(x1);
            float hf0 = __uint_as_float(h0<<16);
            float hf1 = __uint_as_float(h1<<16);
            unsigned int l0 = bf16_rne(x0 - hf0);
            unsigned int l1 = bf16_rne(x1 - hf1);
            hw[j] = h0 | (h1<<16);
            lw[j] = l0 | (l1<<16);
        }
        int pw = (p & 4) | ((p + (i>>1)) & 3);   // swizzled slot
        size_t eo = obase + (size_t)i*DKK + pw*8;
        uint4 hv; hv.x=hw[0]; hv.y=hw[1]; hv.z=hw[2]; hv.w=hw[3];
        uint4 lv; lv.x=lw[0]; lv.y=lw[1]; lv.z=lw[2]; lv.w=lw[3];
        *(uint4*)(Hh + eo) = hv;
        *(uint4*)(Hl + eo) = lv;
    }
}

// C[b][i][j] = (sum_d A[d][i]*B[d][j]) / (sqrt(512)*temp[b]) via split-bf16 MFMA.
// 256x256 tile per block, 8 waves (2Mx4N), BK=32, 16 K-steps.
// 3 phases per K-step (hh, lh, hl) -- best measured schedule (R1, 50.5 us).
// Counted-vmcnt pipeline, never drained to 0 mid-loop; setprio around MFMA.
// NOTE: operand stream (268 MB, ~2x redundancy) is L3-served at ~5.2 TB/s --
// measured invariant across 4 schedule variants => fetch-bound; do not retune.
__global__ __launch_bounds__(512,2) void gemm_mfma(const float* __restrict__ temp,
                                                   float* __restrict__ C) {
    int id   = blockIdx.x;
    int xcd  = id & 7;
    int slot = id >> 3;             // 0..31
    int b    = xcd*2 + (slot >> 4); // batch pinned to XCD (L2 locality)
    int sub  = slot & 15;
    int i0   = (sub >> 2) << 8;
    int j0   = (sub & 3) << 8;
    __shared__ __attribute__((aligned(16))) char lds[131072];
    int t = threadIdx.x;
    int lane = t & 63, w = t >> 6;      // 8 waves
    int wr = w >> 2, wc = w & 3;        // 2 x 4 wave grid, per wave 128x64 out

    int rql = lane >> 2, cl = lane & 3;
    unsigned eoff = (unsigned)(b * (NN*DKK*2));
    unsigned offA = eoff + (unsigned)((i0 + w*32 + rql)*1024) + (unsigned)(cl*16);
    unsigned offB = eoff + (unsigned)((j0 + w*32 + rql)*1024) + (unsigned)(cl*16);
    int dq0 = w*2048;                   // LDS dst base for q=0 (q=1: +1024)

    const char* pAh = (const char*)gAh;
    const char* pAl = (const char*)gAl;
    const char* pBh = (const char*)gBh;
    const char* pBl = (const char*)gBl;
    // LDS unit bases: Ah 0/16384, Al 32768/49152, Bh 65536/81920, Bl 98304/114688

    f32x4 acc[32];
#pragma unroll
    for (int q=0;q<32;q++) acc[q] = (f32x4){0.f,0.f,0.f,0.f};

    int fslot = ((lane>>4) + ((lane&15)>>1)) & 3;
    int faoff = (wr*128 + (lane&15))*64 + fslot*16;   // + mf*1024
    int fboff = (wc*64  + (lane&15))*64 + fslot*16;   // + nf*1024

    // prologue: stage ks=0, issue order AhBh (4), Al (2), Bl (2)
    gl_lds(pAh + offA,          lds + 0      + dq0);
    gl_lds(pAh + offA + 16384,  lds + 0      + dq0 + 1024);
    gl_lds(pBh + offB,          lds + 65536  + dq0);
    gl_lds(pBh + offB + 16384,  lds + 65536  + dq0 + 1024);
    gl_lds(pAl + offA,          lds + 32768  + dq0);
    gl_lds(pAl + offA + 16384,  lds + 32768  + dq0 + 1024);
    gl_lds(pBl + offB,          lds + 98304  + dq0);
    gl_lds(pBl + offB + 16384,  lds + 98304  + dq0 + 1024);

    short8 ah[8], bh[4], al[8], bl[4];

    for (int ks=0; ks<16; ++ks){
        int par = (ks & 1) << 14;       // current buffer parity offset
        int nxt = 16384 - par;

        // ================= phase A : hh =================
        asm volatile("s_waitcnt vmcnt(4)" ::: "memory");
        __builtin_amdgcn_s_barrier();
        __builtin_amdgcn_sched_barrier(0);
        {
            const char* fa = lds + par + faoff;
            const char* fb = lds + 65536 + par + fboff;
#pragma unroll
            for (int mf=0;mf<8;mf++) ah[mf] = *(const short8*)(fa + mf*1024);
#pragma unroll
            for (int nf=0;nf<4;nf++) bh[nf] = *(const short8*)(fb + nf*1024);
        }
        if (ks < 15){
            offA += 64; offB += 64;
            gl_lds(pAh + offA,         lds + 0     + nxt + dq0);
            gl_lds(pAh + offA + 16384, lds + 0     + nxt + dq0 + 1024);
            gl_lds(pBh + offB,         lds + 65536 + nxt + dq0);
            gl_lds(pBh + offB + 16384, lds + 65536 + nxt + dq0 + 1024);
        }
        asm volatile("s_waitcnt lgkmcnt(0)" ::: "memory");
        __builtin_amdgcn_sched_barrier(0);
        __builtin_amdgcn_s_setprio(1);
#pragma unroll
        for (int nf=0;nf<4;nf++)
#pragma unroll
            for (int mf=0;mf<8;mf++)
                acc[mf*4+nf] = __builtin_amdgcn_mfma_f32_16x16x32_bf16(ah[mf], bh[nf], acc[mf*4+nf], 0,0,0);
        __builtin_amdgcn_s_setprio(0);
        __builtin_amdgcn_sched_barrier(0);

        // ================= phase B : lh =================
        if (ks < 15) asm volatile("s_waitcnt vmcnt(6)" ::: "memory");
        else         asm volatile("s_waitcnt vmcnt(2)" ::: "memory");
        __builtin_amdgcn_s_barrier();
        __builtin_amdgcn_sched_barrier(0);
        {
            const char* fa = lds + 32768 + par + faoff;
#pragma unroll
            for (int mf=0;mf<8;mf++) al[mf] = *(const short8*)(fa + mf*1024);
        }
        if (ks < 15){
            gl_lds(pAl + offA,         lds + 32768 + nxt + dq0);
            gl_lds(pAl + offA + 16384, lds + 32768 + nxt + dq0 + 1024);
        }
        asm volatile("s_waitcnt lgkmcnt(0)" ::: "memory");
        __builtin_amdgcn_sched_barrier(0);
        __builtin_amdgcn_s_setprio(1);
#pragma unroll
        for (int nf=0;nf<4;nf++)
#pragma unroll
            for (int mf=0;mf<8;mf++)
                acc[mf*4+nf] = __builtin_amdgcn_mfma_f32_16x16x32_bf16(al[mf], bh[nf], acc[mf*4+nf], 0,0,0);
        __builtin_amdgcn_s_setprio(0);
        __builtin_amdgcn_sched_barrier(0);

        // ================= phase C : hl =================
        if (ks < 15) asm volatile("s_waitcnt vmcnt(6)" ::: "memory");
        else         asm volatile("s_waitcnt vmcnt(0)" ::: "memory");
        __builtin_amdgcn_s_barrier();
        __builtin_amdgcn_sched_barrier(0);
        {
            const char* fb = lds + 98304 + par + fboff;
#pragma unroll
            for (int nf=0;nf<4;nf++) bl[nf] = *(const short8*)(fb + nf*1024);
        }
        if (ks < 15){
            gl_lds(pBl + offB,         lds + 98304 + nxt + dq0);
            gl_lds(pBl + offB + 16384, lds + 98304 + nxt + dq0 + 1024);
        }
        asm volatile("s_waitcnt lgkmcnt(0)" ::: "memory");
        __builtin_amdgcn_sched_barrier(0);
        __builtin_amdgcn_s_setprio(1);
#pragma unroll
        for (int nf=0;nf<4;nf++)
#pragma unroll
            for (int mf=0;mf<8;mf++)
                acc[mf*4+nf] = __builtin_amdgcn_mfma_f32_16x16x32_bf16(ah[mf], bl[nf], acc[mf*4+nf], 0,0,0);
        __builtin_amdgcn_s_setprio(0);
        __builtin_amdgcn_sched_barrier(0);
    }

    float scale = 1.0f/(22.62741699796952f * temp[b]);
    float* Cb = C + ((size_t)b<<20);
    int r0c = i0 + wr*128 + ((lane>>4)<<2);
    int c0c = j0 + wc*64 + (lane&15);
#pragma unroll
    for (int mf=0;mf<8;mf++){
#pragma unroll
        for (int r2=0;r2<4;r2++){
            float* rowp = Cb + (size_t)(r0c + mf*16 + r2)*MM + c0c;
#pragma unroll
            for (int nf=0;nf<4;nf++)
                rowp[nf*16] = acc[mf*4+nf][r2]*scale;
        }
    }
}

// One fused Sinkhorn iteration: block = 16 rows of one batch, tile in LDS.
__global__ __launch_bounds__(256) void sink_iter(const float* __restrict__ S) {
    int b   = blockIdx.y;
    int rb  = blockIdx.x;
    int row0 = rb*RBLK;
    int t = threadIdx.x;
    __shared__ float Ls[RBLK*LSTR];
    __shared__ float v_l[1024];
    __shared__ float u_l[RBLK];

    float4 v4 = *(const float4*)(g_v + (b<<10) + t*4);
    *(float4*)(v_l + t*4) = v4;

    const float* Sb = S + ((size_t)b*NN + row0)*MM;
#pragma unroll
    for (int rr=0; rr<RBLK; ++rr){
        float4 s4 = *(const float4*)(Sb + (size_t)rr*MM + t*4);
        s4.x -= v4.x; s4.y -= v4.y; s4.z -= v4.z; s4.w -= v4.w;
        *(float4*)(&Ls[rr*LSTR + t*4]) = s4;
    }
    __syncthreads();

    {
        int r = t >> 4, c = t & 15;
        const float* Lr = &Ls[r*LSTR + c];
        float m = -INFINITY;
#pragma unroll
        for (int k=0;k<64;k++) m = fmaxf(m, Lr[16*k]);
#pragma unroll
        for (int off=1; off<16; off<<=1) m = fmaxf(m, __shfl_xor(m, off));
        m = fmaxf(m, 0.0f);
        float s = 0.0f;
#pragma unroll
        for (int k=0;k<64;k++) s += __expf(Lr[16*k] - m);
#pragma unroll
        for (int off=1; off<16; off<<=1) s += __shfl_xor(s, off);
        s += __expf(-m);
        float u = m + __logf(s);
        if (c==0){ u_l[r] = u; g_u[b*NN + row0 + r] = u; }
    }
    __syncthreads();

    float mm[4], ss[4];
#pragma unroll
    for (int q=0;q<4;q++){ mm[q]=-INFINITY; ss[q]=0.f; }
#pragma unroll
    for (int r=0;r<RBLK;++r){
        float ur = u_l[r];
        const float* Lr = &Ls[r*LSTR];
#pragma unroll
        for (int q=0;q<4;q++)
            mm[q] = fmaxf(mm[q], Lr[t + 256*q] - ur);
    }
#pragma unroll
    for (int r=0;r<RBLK;++r){
        float ur = u_l[r];
        const float* Lr = &Ls[r*LSTR];
#pragma unroll
        for (int q=0;q<4;q++)
            ss[q] += __expf(Lr[t + 256*q] - ur - mm[q]);
    }
    size_t pbase = ((size_t)(b*NRB + rb) << 10) + t;
#pragma unroll
    for (int q=0;q<4;q++){
        g_pm[pbase + 256*q] = mm[q] + v_l[t + 256*q];
        g_ps[pbase + 256*q] = ss[q];
    }
}

// 8 independent LSE chains over the 64 partials + associative merge.
// 256 blocks x 64 threads: one wave per CU.
__global__ __launch_bounds__(64) void col_lse_combine() {
    int idx = blockIdx.x*64 + threadIdx.x;
    int b = idx >> 10; int j = idx & (MM-1);
    size_t base = ((size_t)(b*NRB) << 10) + j;
    float m[8], s[8];
#pragma unroll
    for (int k=0;k<8;k++){ m[k] = -INFINITY; s[k] = 0.0f; }
    for (int c=0;c<NRB;c+=8){
#pragma unroll
        for (int k=0;k<8;k++){
            float om = g_pm[base + ((size_t)(c+k)<<10)];
            float os = g_ps[base + ((size_t)(c+k)<<10)];
            float nm = fmaxf(m[k], om);
            s[k] = s[k]*__expf(m[k]-nm) + os*__expf(om-nm);
            m[k] = nm;
        }
    }
#pragma unroll
    for (int st=1; st<8; st<<=1){
#pragma unroll
        for (int k=0;k<8;k+=2*st){
            float nm = fmaxf(m[k], m[k+st]);
            s[k] = s[k]*__expf(m[k]-nm) + s[k+st]*__expf(m[k+st]-nm);
            m[k] = nm;
        }
    }
    float nm = fmaxf(m[0], 0.0f);
    float Sx = s[0]*__expf(m[0]-nm) + __expf(-nm);
    g_v[idx] = nm + __logf(Sx);
}

__global__ __launch_bounds__(256) void finalize_rows(float* __restrict__ S,
                                                     const float* __restrict__ tgt) {
    int row  = blockIdx.x*4 + (threadIdx.x>>6);
    int lane = threadIdx.x & 63;
    int b = row >> 10;
    int i = row & (NN-1);
    float ui = g_u[row];
    float4* srow = (float4*)(S + (size_t)row*MM);
    const float4* vb = (const float4*)(g_v + (b<<10));
    const float4* t0 = (const float4*)(tgt + (size_t)b*3*MM);
    const float4* t1 = (const float4*)(tgt + (size_t)b*3*MM + MM);
    const float4* t2 = (const float4*)(tgt + (size_t)b*3*MM + 2*MM);
    float p[16];
    float rs=0.f, a0=0.f, a1=0.f, a2=0.f;
#pragma unroll
    for (int k=0;k<4;k++){
        float4 s4 = srow[lane + 64*k];
        float4 v4 = vb[lane + 64*k];
        p[4*k+0] = __expf(s4.x - ui - v4.x);
        p[4*k+1] = __expf(s4.y - ui - v4.y);
        p[4*k+2] = __expf(s4.z - ui - v4.z);
        p[4*k+3] = __expf(s4.w - ui - v4.w);
        rs += p[4*k+0]+p[4*k+1]+p[4*k+2]+p[4*k+3];
        float4 w0 = t0[lane + 64*k];
        float4 w1 = t1[lane + 64*k];
        float4 w2 = t2[lane + 64*k];
        a0 += p[4*k+0]*w0.x + p[4*k+1]*w0.y + p[4*k+2]*w0.z + p[4*k+3]*w0.w;
        a1 += p[4*k+0]*w1.x + p[4*k+1]*w1.y + p[4*k+2]*w1.z + p[4*k+3]*w1.w;
        a2 += p[4*k+0]*w2.x + p[4*k+1]*w2.y + p[4*k+2]*w2.z + p[4*k+3]*w2.w;
    }
    for (int off=32; off; off>>=1){
        rs += __shfl_xor(rs, off);
        a0 += __shfl_xor(a0, off);
        a1 += __shfl_xor(a1, off);
        a2 += __shfl_xor(a2, off);
    }
    float inv = 1.0f/(rs + 1e-8f);
#pragma unroll
    for (int k=0;k<4;k++){
        srow[lane + 64*k] = make_float4(p[4*k+0]*inv, p[4*k+1]*inv, p[4*k+2]*inv, p[4*k+3]*inv);
    }
    if (lane==0){
        g_w[row] = rs;
        g_wt[(b*3+0)*NN + i] = a0*inv;
        g_wt[(b*3+1)*NN + i] = a1*inv;
        g_wt[(b*3+2)*NN + i] = a2*inv;
    }
}

// Register-resident 3-pass Procrustes: each thread loads its 28 values once,
// reductions via wave shuffle + 4-partial LDS combine (3 barriers total).
__global__ __launch_bounds__(256) void procrustes(const float* __restrict__ src,
                                                  float* __restrict__ out) {
    int b = blockIdx.x;
    int t = threadIdx.x;
    int lane = t & 63, w = t >> 6;
    __shared__ float part[4][16];
    const float* wrow = g_w + b*NN;
    const float* sb  = src  + (size_t)b*3*NN;
    const float* wtb = g_wt + (size_t)b*3*NN;

    float wv[4], sv[3][4], tv3[3][4];
#pragma unroll
    for (int k=0;k<4;k++){
        int i = t + 256*k;
        wv[k] = wrow[i];
#pragma unroll
        for (int c=0;c<3;c++){
            sv[c][k]  = sb[c*NN+i];
            tv3[c][k] = wtb[c*NN+i];
        }
    }

    auto block_reduce = [&](float* v, int nv){
        for (int jx=0;jx<nv;jx++){
            float x = v[jx];
            for (int off=32;off;off>>=1) x += __shfl_xor(x, off);
            if (lane==0) part[w][jx] = x;
        }
        __syncthreads();
        for (int jx=0;jx<nv;jx++)
            v[jx] = part[0][jx]+part[1][jx]+part[2][jx]+part[3][jx];
        __syncthreads();
    };

    float W = wv[0]+wv[1]+wv[2]+wv[3];
    block_reduce(&W, 1);
    float winv = 1.0f/(W + 1e-8f);
    float wn[4];
#pragma unroll
    for (int k=0;k<4;k++) wn[k] = wv[k]*winv;

    float a[6];
#pragma unroll
    for (int c=0;c<3;c++){
        float p1=0.f,p2=0.f;
#pragma unroll
        for (int k=0;k<4;k++){ p1 += sv[c][k]*wn[k]; p2 += tv3[c][k]*wn[k]; }
        a[c]=p1; a[3+c]=p2;
    }
    block_reduce(a, 6);
    float sc[3], tc[3];
#pragma unroll
    for (int c=0;c<3;c++){ sc[c]=a[c]; tc[c]=a[3+c]; }

    float H[9];
#pragma unroll
    for (int c=0;c<3;c++)
#pragma unroll
        for (int d=0;d<3;d++){
            float p=0.f;
#pragma unroll
            for (int k=0;k<4;k++)
                p += (sv[c][k]-sc[c]) * ((tv3[d][k]-tc[d])*wn[k]);
            H[c*3+d]=p;
        }
    block_reduce(H, 9);

    if (t==0){
        double Hd[3][3];
        for (int r2=0;r2<3;r2++) for (int c2=0;c2<3;c2++) Hd[r2][c2]=H[r2*3+c2];
        double K[3][3];
        for (int i2=0;i2<3;i2++)
            for (int j2=0;j2<3;j2++){
                double acc=0;
                for (int r2=0;r2<3;r2++) acc += Hd[r2][i2]*Hd[r2][j2];
                K[i2][j2]=acc;
            }
        double V[3][3]={{1,0,0},{0,1,0},{0,0,1}};
        const int PQ[3][2]={{0,1},{0,2},{1,2}};
        for (int sweep=0; sweep<30; ++sweep){
            double off = fabs(K[0][1])+fabs(K[0][2])+fabs(K[1][2]);
            if (off < 1e-26) break;
            for (int pi=0; pi<3; ++pi){
                int p = PQ[pi][0], q = PQ[pi][1];
                double apq = K[p][q];
                if (fabs(apq) < 1e-300) continue;
                double tau = (K[q][q]-K[p][p])/(2.0*apq);
                double tt  = (tau>=0.0?1.0:-1.0)/(fabs(tau)+sqrt(1.0+tau*tau));
                double c   = 1.0/sqrt(1.0+tt*tt);
                double s   = tt*c;
                double Kpp=K[p][p], Kqq=K[q][q];
                K[p][p] = Kpp - tt*apq;
                K[q][q] = Kqq + tt*apq;
                K[p][q] = 0.0; K[q][p] = 0.0;
                int r2 = 3-p-q;
                double Krp=K[r2][p], Krq=K[r2][q];
                K[r2][p] = c*Krp - s*Krq; K[p][r2]=K[r2][p];
                K[r2][q] = s*Krp + c*Krq; K[q][r2]=K[r2][q];
                for (int rr=0; rr<3; ++rr){
                    double vp=V[rr][p], vq=V[rr][q];
                    V[rr][p] = c*vp - s*vq;
                    V[rr][q] = s*vp + c*vq;
                }
            }
        }
        double lam[3]={K[0][0],K[1][1],K[2][2]};
        int o0=0,o1=1,o2=2,tmp;
        if (lam[o0]<lam[o1]){tmp=o0;o0=o1;o1=tmp;}
        if (lam[o0]<lam[o2]){tmp=o0;o0=o2;o2=tmp;}
        if (lam[o1]<lam[o2]){tmp=o1;o1=o2;o2=tmp;}
        int ord[3]={o0,o1,o2};
        double Vs[3][3], U[3][3];
        for (int k=0;k<3;k++)
            for (int r2=0;r2<3;r2++) Vs[r2][k]=V[r2][ord[k]];
        for (int k=0;k<3;k++){
            double ux = Hd[0][0]*Vs[0][k] + Hd[0][1]*Vs[1][k] + Hd[0][2]*Vs[2][k];
            double uy = Hd[1][0]*Vs[0][k] + Hd[1][1]*Vs[1][k] + Hd[1][2]*Vs[2][k];
            double uz = Hd[2][0]*Vs[0][k] + Hd[2][1]*Vs[1][k] + Hd[2][2]*Vs[2][k];
            double n = sqrt(ux*ux+uy*uy+uz*uz);
            if (n > 1e-30){ U[0][k]=ux/n; U[1][k]=uy/n; U[2][k]=uz/n; }
            else {
                double cx = U[1][0]*U[2][1]-U[2][0]*U[1][1];
                double cy = U[2][0]*U[0][1]-U[0][0]*U[2][1];
                double cz = U[0][0]*U[1][1]-U[1][0]*U[0][1];
                U[0][k]=cx; U[1][k]=cy; U[2][k]=cz;
            }
        }
        double rm[3][3];
        for (int i2=0;i2<3;i2++)
            for (int j2=0;j2<3;j2++)
                rm[i2][j2] = Vs[i2][0]*U[j2][0] + Vs[i2][1]*U[j2][1] + Vs[i2][2]*U[j2][2];
        double det = rm[0][0]*(rm[1][1]*rm[2][2]-rm[1][2]*rm[2][1])
                   - rm[0][1]*(rm[1][0]*rm[2][2]-rm[1][2]*rm[2][0])
                   + rm[0][2]*(rm[1][0]*rm[2][1]-rm[1][1]*rm[2][0]);
        double R[3][3];
        for (int i2=0;i2<3;i2++)
            for (int j2=0;j2<3;j2++)
                R[i2][j2] = Vs[i2][0]*U[j2][0] + Vs[i2][1]*U[j2][1] + det*Vs[i2][2]*U[j2][2];
        double tvv[3];
        for (int i2=0;i2<3;i2++)
            tvv[i2] = -(R[i2][0]*sc[0]+R[i2][1]*sc[1]+R[i2][2]*sc[2]) + tc[i2];
        for (int i2=0;i2<3;i2++)
            for (int j2=0;j2<3;j2++)
                out[b*9 + i2*3 + j2] = (float)R[i2][j2];
        for (int i2=0;i2<3;i2++)
            out[144 + b*3 + i2] = (float)tvv[i2];
    }
}

extern "C" void kernel_launch(void* const* d_in, const int* in_sizes, int n_in,
                              void* d_out, int out_size, void* d_ws, size_t ws_size,
                              hipStream_t stream) {
    const float* src_emb = (const float*)d_in[0];
    const float* tgt_emb = (const float*)d_in[1];
    const float* src     = (const float*)d_in[2];
    const float* tgt     = (const float*)d_in[3];
    const float* temp    = (const float*)d_in[4];
    float* out = (float*)d_out;
    float* S = out + 192;   // perm_norm region doubles as scores buffer

    hipLaunchKernelGGL(convert_split, dim3(16,8,32), dim3(256), 0, stream, src_emb, tgt_emb);
    hipLaunchKernelGGL(gemm_mfma, dim3(256), dim3(512), 0, stream, temp, S);
    for (int it=0; it<5; ++it){
        hipLaunchKernelGGL(sink_iter, dim3(NRB,BB), dim3(256), 0, stream, S);
        hipLaunchKernelGGL(col_lse_combine, dim3(256), dim3(64), 0, stream);
    }
    hipLaunchKernelGGL(finalize_rows, dim3(4096), dim3(256), 0, stream, S, tgt);
    hipLaunchKernelGGL(procrustes, dim3(16), dim3(256), 0, stream, src, out);
}